// Round 15
// baseline (1168.662 us; speedup 1.0000x reference)
//
#include <hip/hip_runtime.h>

#define Bq 8
#define Nq 4096
#define Dq 128
#define Hq 8
#define FFq 512
#define KNNq 16
#define Lq 2
#define DHq 16
#define EPSq 1e-5f

typedef _Float16 half4 __attribute__((ext_vector_type(4)));
typedef _Float16 half2t __attribute__((ext_vector_type(2)));
typedef float v4f __attribute__((ext_vector_type(4)));

static __device__ __forceinline__ half2t pkrtz(float a, float b) {
    return __builtin_bit_cast(half2t, __builtin_amdgcn_cvt_pkrtz(a, b));
}

// ---------------- fused prep: feat (f16) + weight fp32->f16 conversion ----------------
__global__ __launch_bounds__(256) void prep_kernel(const float* __restrict__ x,
                                                   const float* __restrict__ xyz_w,
                                                   const float* __restrict__ xyz_b,
                                                   const float* __restrict__ ohe_w,
                                                   const float* __restrict__ ohe_b,
                                                   _Float16* __restrict__ feat16,
                                                   const float* __restrict__ ipw,
                                                   const float* __restrict__ opw,
                                                   const float* __restrict__ l1w,
                                                   const float* __restrict__ l2w,
                                                   _Float16* __restrict__ wb) {
    int bid = blockIdx.x;
    if (bid < 16384) {
        int i = bid * 256 + threadIdx.x;
        int d = i & 127;
        int t = i >> 7;
        const float* xr = x + (size_t)t * 8;
        float s = xyz_b[d] + ohe_b[d];
        s += xr[0] * xyz_w[d * 3 + 0] + xr[1] * xyz_w[d * 3 + 1] + xr[2] * xyz_w[d * 3 + 2];
        s += xr[3] * ohe_w[d * 5 + 0] + xr[4] * ohe_w[d * 5 + 1] + xr[5] * ohe_w[d * 5 + 2]
           + xr[6] * ohe_w[d * 5 + 3] + xr[7] * ohe_w[d * 5 + 4];
        feat16[i] = (_Float16)s;
    } else {
        int i = (bid - 16384) * 256 + threadIdx.x;
        float v;
        if (i < 98304) v = ipw[i];
        else if (i < 131072) v = opw[i - 98304];
        else if (i < 262144) v = l1w[i - 131072];
        else v = l2w[i - 262144];
        wb[i] = (_Float16)v;
    }
}

// ---------------- KNN top-16 v6: dual chains, 48 KB LDS (3 blocks/CU), md aliased (R14 champ) ----------------
__global__ __launch_bounds__(256) void knn_kernel(const float* __restrict__ x, int* __restrict__ idx) {
    __shared__ __attribute__((aligned(16))) float sx[Nq];
    __shared__ __attribute__((aligned(16))) float sy[Nq];
    __shared__ __attribute__((aligned(16))) float sz[Nq];
    unsigned int (*md)[17] = (unsigned int (*)[17])sx;
    int b = blockIdx.y;
    int tid = threadIdx.x;
    for (int p = tid; p < Nq; p += 256) {
        const float* xr = x + ((size_t)b * Nq + p) * 8;
        sx[p] = xr[0]; sy[p] = xr[1]; sz[p] = xr[2];
    }
    __syncthreads();
    int qi = tid >> 3;
    int part = tid & 7;
    int n = blockIdx.x * 32 + qi;
    float qx = sx[n], qy = sy[n], qz = sz[n];
    unsigned int bdA[KNNq], bdB[KNNq];
#pragma unroll
    for (int i = 0; i < KNNq; i++) { bdA[i] = 0xFFFFFFFFu; bdB[i] = 0xFFFFFFFFu; }
    int j0 = part * 512;
    int rot = part;
    for (int jj = 0; jj < 256; jj++) {
        int j1 = j0 + ((jj + rot) & 511);
        int j2 = j0 + ((jj + 256 + rot) & 511);
        float p1x = sx[j1], p1y = sy[j1], p1z = sz[j1];
        float p2x = sx[j2], p2y = sy[j2], p2z = sz[j2];
        float dx1 = qx - p1x, dy1 = qy - p1y, dz1 = qz - p1z;
        float dx2 = qx - p2x, dy2 = qy - p2y, dz2 = qz - p2z;
        float d21 = fmaf(dx1, dx1, fmaf(dy1, dy1, dz1 * dz1));
        float d22 = fmaf(dx2, dx2, fmaf(dy2, dy2, dz2 * dz2));
        unsigned int k1 = (__float_as_uint(d21) & 0xFFFFF000u) | (unsigned int)j1;
        unsigned int k2 = (__float_as_uint(d22) & 0xFFFFF000u) | (unsigned int)j2;
        k1 = (j1 == n) ? 0xFFFFFFFFu : k1;
        k2 = (j2 == n) ? 0xFFFFFFFFu : k2;
#pragma unroll
        for (int i = 0; i < KNNq; i++) {
            unsigned int loA = bdA[i] < k1 ? bdA[i] : k1;
            unsigned int hiA = bdA[i] < k1 ? k1 : bdA[i];
            bdA[i] = loA; k1 = hiA;
            unsigned int loB = bdB[i] < k2 ? bdB[i] : k2;
            unsigned int hiB = bdB[i] < k2 ? k2 : bdB[i];
            bdB[i] = loB; k2 = hiB;
        }
    }
#pragma unroll
    for (int t = 0; t < KNNq; t++) {
        unsigned int key = bdB[t];
#pragma unroll
        for (int i = 0; i < KNNq; i++) {
            unsigned int lo = bdA[i] < key ? bdA[i] : key;
            unsigned int hi = bdA[i] < key ? key : bdA[i];
            bdA[i] = lo; key = hi;
        }
    }
    __syncthreads();
#pragma unroll
    for (int i = 0; i < KNNq; i++) md[tid][i] = bdA[i];
    __syncthreads();
    if (part == 0) {
        unsigned int pall = 0;
        int* op = idx + ((size_t)b * Nq + n) * KNNq;
        int base_row = qi * 8;
#pragma unroll
        for (int s = 0; s < KNNq; s++) {
            unsigned int best = 0xFFFFFFFFu; int bp = 0;
#pragma unroll
            for (int p2 = 0; p2 < 8; p2++) {
                unsigned int ptr = (pall >> (p2 * 4)) & 15u;
                unsigned int v = md[base_row + p2][ptr];
                if (v < best) { best = v; bp = p2; }
            }
            op[s] = (int)(best & 4095u);
            pall += (1u << (bp * 4));
        }
    }
}

// ---------------- KNN attention: f16 gathers, f32 math, emits h16 only ----------------
__global__ __launch_bounds__(256, 4) void knn_attn_kernel(const _Float16* __restrict__ feat16,
                                                          const int* __restrict__ idx,
                                                          _Float16* __restrict__ h16) {
    int wave = threadIdx.x >> 6;
    int lane = threadIdx.x & 63;
    int token = blockIdx.x * 4 + wave;
    int b = token >> 12;
    half2t fh = ((const half2t*)(feat16 + (size_t)token * Dq))[lane];
    float2 f = make_float2((float)fh[0], (float)fh[1]);
    const int* ip = idx + (size_t)token * KNNq;
    int jj[KNNq];
#pragma unroll
    for (int k = 0; k < KNNq; k++) jj[k] = ip[k];
    float2 g[KNNq];
#pragma unroll
    for (int k = 0; k < KNNq; k++) {
        half2t gh = ((const half2t*)(feat16 + (((size_t)b << 12) + jj[k]) * Dq))[lane];
        g[k] = make_float2((float)gh[0], (float)gh[1]);
    }
    float sc[KNNq];
#pragma unroll
    for (int k = 0; k < KNNq; k++) {
        float p = f.x * g[k].x + f.y * g[k].y;
#pragma unroll
        for (int m = 1; m < 64; m <<= 1) p += __shfl_xor(p, m);
        sc[k] = p * 0.088388347648318447f; // 1/sqrt(128)
    }
    float mx = sc[0];
#pragma unroll
    for (int k = 1; k < KNNq; k++) mx = fmaxf(mx, sc[k]);
    float sum = 0.f;
#pragma unroll
    for (int k = 0; k < KNNq; k++) { sc[k] = __expf(sc[k] - mx); sum += sc[k]; }
    float inv = 1.f / sum;
    float o0 = 0.f, o1 = 0.f;
#pragma unroll
    for (int k = 0; k < KNNq; k++) { o0 += sc[k] * g[k].x; o1 += sc[k] * g[k].y; }
    ((half2t*)(h16 + (size_t)token * Dq))[lane] = pkrtz(o0 * inv, o1 * inv);
}

// ---------------- f16 MFMA GEMM, LDS-free ----------------
// MODE 2: qkv pack — Q (pre-scaled by 0.25*log2e) and K to pk[sel][bh][n][16],
// V TRANSPOSED to slot2 as Vt[bh][d][n].
template <int MODE>
__global__ __launch_bounds__(256) void hgemm_kernel(const _Float16* __restrict__ A,
                                                    const _Float16* __restrict__ W,
                                                    const float* __restrict__ bias,
                                                    void* __restrict__ Cout,
                                                    int M, int Nc, int K) {
    int tid = threadIdx.x;
    int lane = tid & 63, w = tid >> 6;
    int l15 = lane & 15, l4 = lane >> 4;
    int m0 = blockIdx.y * 64 + w * 16;
    int n0 = blockIdx.x * 64;
    const _Float16* Ap = A + (size_t)(m0 + l15) * K + l4 * 4;
    const _Float16* Wp = W + (size_t)(n0 + l15) * K + l4 * 4;
    v4f acc[4] = {{0.f, 0.f, 0.f, 0.f}, {0.f, 0.f, 0.f, 0.f}, {0.f, 0.f, 0.f, 0.f}, {0.f, 0.f, 0.f, 0.f}};
    for (int ks = 0; ks < K; ks += 16) {
        half4 af = *(const half4*)(Ap + ks);
#pragma unroll
        for (int nt = 0; nt < 4; nt++) {
            half4 wf = *(const half4*)(Wp + (size_t)nt * 16 * K + ks);
            acc[nt] = __builtin_amdgcn_mfma_f32_16x16x16f16(wf, af, acc[nt], 0, 0, 0);
        }
    }
    int m = m0 + l15;
#pragma unroll
    for (int nt = 0; nt < 4; nt++) {
        int nb = n0 + nt * 16 + l4 * 4;
        float4 bv = *(const float4*)(bias + nb);
        float v0 = acc[nt][0] + bv.x, v1 = acc[nt][1] + bv.y;
        float v2 = acc[nt][2] + bv.z, v3 = acc[nt][3] + bv.w;
        int n_base = n0 + nt * 16;
        int sel = n_base >> 7;
        if (MODE == 2 && sel == 0) {
            v0 *= 0.36067376f; v1 *= 0.36067376f; v2 *= 0.36067376f; v3 *= 0.36067376f;
        }
        half2t lo = pkrtz(v0, v1);
        half2t hi = pkrtz(v2, v3);
        half4 hv; hv[0] = lo[0]; hv[1] = lo[1]; hv[2] = hi[0]; hv[3] = hi[1];
        if (sel < 2) {
            int hh = (n_base >> 4) & 7;
            size_t base = (size_t)sel * (64ull * Nq * 16)
                        + ((size_t)((m >> 12) * 8 + hh)) * (Nq * 16)
                        + (size_t)(m & 4095) * 16 + l4 * 4;
            *(half4*)((_Float16*)Cout + base) = hv;
        } else {
            int hh = (n_base >> 4) & 7;
            size_t vb = 2ull * 64 * Nq * 16
                      + ((size_t)((m >> 12) * 8 + hh)) * (16 * Nq)
                      + (size_t)(m & 4095);
            _Float16* vp = (_Float16*)Cout + vb + (size_t)(l4 * 4) * Nq;
            vp[0 * Nq] = hv[0]; vp[1 * Nq] = hv[1]; vp[2 * Nq] = hv[2]; vp[3 * Nq] = hv[3];
        }
    }
}

// ---------------- flash v8: BK=128 key tiles (half the barriers), scalar lsum (flash5-measured) ----------------
// pk: Q,K = [sel][bh][n][16]; V = Vt[bh][d][n]. grid (N/64, B*H), 4 waves x 16 queries.
__global__ __launch_bounds__(256) void flash8_kernel(const _Float16* __restrict__ pk,
                                                     _Float16* __restrict__ out16) {
    __shared__ _Float16 Ks[2][128 * 20];   // K rows, padded pitch 20 (10.2 KB)
    __shared__ _Float16 Vs[2][16 * 130];   // V^T rows, pitch 130 (odd word stride) (8.3 KB)
    int tid = threadIdx.x;
    int lane = tid & 63, w = tid >> 6;
    int bh = blockIdx.y;
    const _Float16* Qb = pk + (size_t)bh * (Nq * 16);
    const _Float16* Kb = pk + (size_t)(64 + bh) * (Nq * 16);
    const _Float16* Vt = pk + 2ull * 64 * Nq * 16 + (size_t)bh * (16 * Nq);
    int q0 = blockIdx.x * 64 + w * 16;
    int l15 = lane & 15, l4 = lane >> 4;

    half4 qf = *(const half4*)(Qb + (size_t)(q0 + l15) * 16 + l4 * 4);

    // staging: 2 half4 per thread per buffer. K: e=tid+256i -> row e>>2, grp e&3.
    // V: e -> d-row e>>5, key-grp (e&31)*4.
    int kr0 = tid >> 2, kc0 = (tid & 3) * 4;
    int kr1 = (tid + 256) >> 2, kc1 = ((tid + 256) & 3) * 4;
    int vd0 = tid >> 5, vj0 = (tid & 31) * 4;
    int vd1 = (tid + 256) >> 5, vj1 = ((tid + 256) & 31) * 4;

    {
        *(half4*)(Ks[0] + kr0 * 20 + kc0) = *(const half4*)(Kb + (size_t)kr0 * 16 + kc0);
        *(half4*)(Ks[0] + kr1 * 20 + kc1) = *(const half4*)(Kb + (size_t)kr1 * 16 + kc1);
        *(half4*)(Vs[0] + vd0 * 130 + vj0) = *(const half4*)(Vt + (size_t)vd0 * Nq + vj0);
        *(half4*)(Vs[0] + vd1 * 130 + vj1) = *(const half4*)(Vt + (size_t)vd1 * Nq + vj1);
    }
    __syncthreads();

    v4f o = {0.f, 0.f, 0.f, 0.f};
    float lsum = 0.f;
    const int T = Nq / 128;

    for (int kt = 0; kt < T; kt++) {
        int cur = kt & 1, nxt = cur ^ 1;
        if (kt < T - 1) {
            const _Float16* Kn = Kb + (size_t)(kt + 1) * 128 * 16;
            const _Float16* Vn = Vt + (kt + 1) * 128;
            *(half4*)(Ks[nxt] + kr0 * 20 + kc0) = *(const half4*)(Kn + (size_t)kr0 * 16 + kc0);
            *(half4*)(Ks[nxt] + kr1 * 20 + kc1) = *(const half4*)(Kn + (size_t)kr1 * 16 + kc1);
            *(half4*)(Vs[nxt] + vd0 * 130 + vj0) = *(const half4*)(Vn + (size_t)vd0 * Nq + vj0);
            *(half4*)(Vs[nxt] + vd1 * 130 + vj1) = *(const half4*)(Vn + (size_t)vd1 * Nq + vj1);
        }
        // S^T = K @ Q^T over 8 key-groups of 16
        v4f S[8];
#pragma unroll
        for (int g = 0; g < 8; g++) {
            half4 kf = *(const half4*)(Ks[cur] + (g * 16 + l15) * 20 + l4 * 4);
            S[g] = __builtin_amdgcn_mfma_f32_16x16x16f16(kf, qf, (v4f){0.f, 0.f, 0.f, 0.f}, 0, 0, 0);
        }
        // P = 2^S (no-max softmax, bounded scores); lsum via scalar adds (flash5-measured better)
        half4 P[8];
#pragma unroll
        for (int g = 0; g < 8; g++) {
            float p0 = __builtin_amdgcn_exp2f(S[g][0]);
            float p1 = __builtin_amdgcn_exp2f(S[g][1]);
            float p2 = __builtin_amdgcn_exp2f(S[g][2]);
            float p3 = __builtin_amdgcn_exp2f(S[g][3]);
            lsum += (p0 + p1) + (p2 + p3);
            half2t lo = pkrtz(p0, p1);
            half2t hi = pkrtz(p2, p3);
            P[g][0] = lo[0]; P[g][1] = lo[1]; P[g][2] = hi[0]; P[g][3] = hi[1];
        }
        // O^T += V^T @ P^T
#pragma unroll
        for (int g = 0; g < 8; g++) {
            half4 vf = *(const half4*)(Vs[cur] + l15 * 130 + g * 16 + l4 * 4);
            o = __builtin_amdgcn_mfma_f32_16x16x16f16(vf, P[g], o, 0, 0, 0);
        }
        __syncthreads();
    }
    lsum += __shfl_xor(lsum, 16);
    lsum += __shfl_xor(lsum, 32);
    float inv = 1.f / lsum;
    int row = q0 + l15;
    int b = bh >> 3, hh = bh & 7;
    half2t lo = pkrtz(o[0] * inv, o[1] * inv);
    half2t hi = pkrtz(o[2] * inv, o[3] * inv);
    half4 hv; hv[0] = lo[0]; hv[1] = lo[1]; hv[2] = hi[0]; hv[3] = hi[1];
    *(half4*)(out16 + ((size_t)(b * Nq + row)) * Dq + hh * 16 + l4 * 4) = hv;
}

// ---------------- fused GEMM(Nc=128) + residual(h16) + LayerNorm -> h16 ----------------
__global__ __launch_bounds__(256) void hgemm_ln_kernel(const _Float16* __restrict__ A,
                                                       const _Float16* __restrict__ W,
                                                       const float* __restrict__ bias,
                                                       const float* __restrict__ lnw,
                                                       const float* __restrict__ lnb,
                                                       _Float16* __restrict__ h16,
                                                       int K) {
    int tid = threadIdx.x;
    int lane = tid & 63, w = tid >> 6;
    int l15 = lane & 15, l4 = lane >> 4;
    int m0 = blockIdx.x * 64 + w * 16;
    const _Float16* Ap = A + (size_t)(m0 + l15) * K + l4 * 4;
    const _Float16* Wp = W + (size_t)l15 * K + l4 * 4;
    v4f acc[8] = {};
    for (int ks = 0; ks < K; ks += 16) {
        half4 af = *(const half4*)(Ap + ks);
#pragma unroll
        for (int nt = 0; nt < 8; nt++) {
            half4 wf = *(const half4*)(Wp + (size_t)nt * 16 * K + ks);
            acc[nt] = __builtin_amdgcn_mfma_f32_16x16x16f16(wf, af, acc[nt], 0, 0, 0);
        }
    }
    int m = m0 + l15;
    float x[8][4];
    float psum = 0.f;
#pragma unroll
    for (int nt = 0; nt < 8; nt++) {
        int nb = nt * 16 + l4 * 4;
        float4 bv = *(const float4*)(bias + nb);
        half4 rv = *(const half4*)(h16 + (size_t)m * Dq + nb);
        x[nt][0] = acc[nt][0] + bv.x + (float)rv[0];
        x[nt][1] = acc[nt][1] + bv.y + (float)rv[1];
        x[nt][2] = acc[nt][2] + bv.z + (float)rv[2];
        x[nt][3] = acc[nt][3] + bv.w + (float)rv[3];
        psum += (x[nt][0] + x[nt][1]) + (x[nt][2] + x[nt][3]);
    }
    psum += __shfl_xor(psum, 16);
    psum += __shfl_xor(psum, 32);
    float mean = psum * (1.f / 128.f);
    float vsum = 0.f;
#pragma unroll
    for (int nt = 0; nt < 8; nt++)
#pragma unroll
        for (int r = 0; r < 4; r++) {
            x[nt][r] -= mean;
            vsum += x[nt][r] * x[nt][r];
        }
    vsum += __shfl_xor(vsum, 16);
    vsum += __shfl_xor(vsum, 32);
    float inv = rsqrtf(vsum * (1.f / 128.f) + EPSq);
#pragma unroll
    for (int nt = 0; nt < 8; nt++) {
        int nb = nt * 16 + l4 * 4;
        float4 wv = *(const float4*)(lnw + nb);
        float4 bb = *(const float4*)(lnb + nb);
        float y0 = x[nt][0] * inv * wv.x + bb.x;
        float y1 = x[nt][1] * inv * wv.y + bb.y;
        float y2 = x[nt][2] * inv * wv.z + bb.z;
        float y3 = x[nt][3] * inv * wv.w + bb.w;
        half2t lo = pkrtz(y0, y1);
        half2t hi = pkrtz(y2, y3);
        half4 hv2; hv2[0] = lo[0]; hv2[1] = lo[1]; hv2[2] = hi[0]; hv2[3] = hi[1];
        *(half4*)(h16 + (size_t)m * Dq + nb) = hv2;
    }
}

// ---------------- fused FFN (+ LN). LAST=1: emit per-wave column partial sums for pooling ----------------
template <int LAST>
__global__ __launch_bounds__(256) void ffn_kernel(const _Float16* __restrict__ h16in,
                                                  const _Float16* __restrict__ W1,
                                                  const float* __restrict__ b1,
                                                  const _Float16* __restrict__ W2,
                                                  const float* __restrict__ b2,
                                                  const float* __restrict__ lnw,
                                                  const float* __restrict__ lnb,
                                                  _Float16* __restrict__ h16,
                                                  float* __restrict__ part) {
    int tid = threadIdx.x;
    int lane = tid & 63, w = tid >> 6;
    int l15 = lane & 15, l4 = lane >> 4;
    int m0 = blockIdx.x * 64 + w * 16;
    int m = m0 + l15;
    const _Float16* Ap = h16in + (size_t)m * Dq + l4 * 4;
    half4 afr[8];
#pragma unroll
    for (int t = 0; t < 8; t++) afr[t] = *(const half4*)(Ap + t * 16);
    half4 mid[32];
#pragma unroll
    for (int c = 0; c < 8; c++) {
        v4f acc[4] = {};
#pragma unroll
        for (int t = 0; t < 8; t++) {
#pragma unroll
            for (int nt = 0; nt < 4; nt++) {
                half4 wf = *(const half4*)(W1 + (size_t)(c * 64 + nt * 16 + l15) * 128 + t * 16 + l4 * 4);
                acc[nt] = __builtin_amdgcn_mfma_f32_16x16x16f16(wf, afr[t], acc[nt], 0, 0, 0);
            }
        }
#pragma unroll
        for (int nt = 0; nt < 4; nt++) {
            float4 bv = *(const float4*)(b1 + c * 64 + nt * 16 + l4 * 4);
            float v0 = fmaxf(acc[nt][0] + bv.x, 0.f);
            float v1 = fmaxf(acc[nt][1] + bv.y, 0.f);
            float v2 = fmaxf(acc[nt][2] + bv.z, 0.f);
            float v3 = fmaxf(acc[nt][3] + bv.w, 0.f);
            half2t lo = pkrtz(v0, v1), hi = pkrtz(v2, v3);
            half4 hv; hv[0] = lo[0]; hv[1] = lo[1]; hv[2] = hi[0]; hv[3] = hi[1];
            mid[c * 4 + nt] = hv;
        }
    }
    v4f acc8[8] = {};
#pragma unroll 4
    for (int t = 0; t < 32; t++) {
#pragma unroll
        for (int nt = 0; nt < 8; nt++) {
            half4 wf = *(const half4*)(W2 + (size_t)(nt * 16 + l15) * 512 + t * 16 + l4 * 4);
            acc8[nt] = __builtin_amdgcn_mfma_f32_16x16x16f16(wf, mid[t], acc8[nt], 0, 0, 0);
        }
    }
    float x[8][4];
    float psum = 0.f;
#pragma unroll
    for (int nt = 0; nt < 8; nt++) {
        int nb = nt * 16 + l4 * 4;
        float4 bv = *(const float4*)(b2 + nb);
        x[nt][0] = acc8[nt][0] + bv.x + (float)afr[nt][0];
        x[nt][1] = acc8[nt][1] + bv.y + (float)afr[nt][1];
        x[nt][2] = acc8[nt][2] + bv.z + (float)afr[nt][2];
        x[nt][3] = acc8[nt][3] + bv.w + (float)afr[nt][3];
        psum += (x[nt][0] + x[nt][1]) + (x[nt][2] + x[nt][3]);
    }
    psum += __shfl_xor(psum, 16);
    psum += __shfl_xor(psum, 32);
    float mean = psum * (1.f / 128.f);
    float vsum = 0.f;
#pragma unroll
    for (int nt = 0; nt < 8; nt++)
#pragma unroll
        for (int r = 0; r < 4; r++) {
            x[nt][r] -= mean;
            vsum += x[nt][r] * x[nt][r];
        }
    vsum += __shfl_xor(vsum, 16);
    vsum += __shfl_xor(vsum, 32);
    float inv = rsqrtf(vsum * (1.f / 128.f) + EPSq);
#pragma unroll
    for (int nt = 0; nt < 8; nt++) {
        int nb = nt * 16 + l4 * 4;
        float4 wv = *(const float4*)(lnw + nb);
        float4 bb = *(const float4*)(lnb + nb);
        x[nt][0] = x[nt][0] * inv * wv.x + bb.x;
        x[nt][1] = x[nt][1] * inv * wv.y + bb.y;
        x[nt][2] = x[nt][2] * inv * wv.z + bb.z;
        x[nt][3] = x[nt][3] * inv * wv.w + bb.w;
        if (!LAST) {
            half2t lo = pkrtz(x[nt][0], x[nt][1]);
            half2t hi = pkrtz(x[nt][2], x[nt][3]);
            half4 hv2; hv2[0] = lo[0]; hv2[1] = lo[1]; hv2[2] = hi[0]; hv2[3] = hi[1];
            *(half4*)(h16 + (size_t)m * Dq + nb) = hv2;
        }
    }
    if (LAST) {
#pragma unroll
        for (int nt = 0; nt < 8; nt++)
#pragma unroll
            for (int r = 0; r < 4; r++) {
                float v = x[nt][r];
                v += __shfl_xor(v, 1);
                v += __shfl_xor(v, 2);
                v += __shfl_xor(v, 4);
                v += __shfl_xor(v, 8);
                x[nt][r] = v;
            }
        if (l15 == 0) {
            float* pp = part + ((size_t)blockIdx.x * 4 + w) * Dq;
#pragma unroll
            for (int nt = 0; nt < 8; nt++)
#pragma unroll
                for (int r = 0; r < 4; r++)
                    pp[nt * 16 + l4 * 4 + r] = x[nt][r];
        }
    }
}

// ---------------- head: pooled = mean over N via 256 wave-partials; MLP + sigmoid ----------------
__global__ __launch_bounds__(512) void head_kernel(const float* __restrict__ part,
                                                   const float* __restrict__ fc1_w, const float* __restrict__ fc1_b,
                                                   const float* __restrict__ fc2_w, const float* __restrict__ fc2_b,
                                                   float* __restrict__ out) {
    __shared__ float psh[Dq];
    __shared__ float red[512];
    int b = blockIdx.x, f = threadIdx.x;
    if (f < Dq) {
        float s = 0.f;
        for (int c = 0; c < 256; c++) s += part[((size_t)b * 256 + c) * Dq + f];
        psh[f] = s * (1.f / 4096.f);
    }
    __syncthreads();
    const float* wr = fc1_w + (size_t)f * Dq;
    float s = fc1_b[f];
    for (int d = 0; d < Dq; d++) s += psh[d] * wr[d];
    red[f] = fmaxf(s, 0.f) * fc2_w[f];
    __syncthreads();
    for (int st = 256; st > 0; st >>= 1) {
        if (f < st) red[f] += red[f + st];
        __syncthreads();
    }
    if (f == 0) out[b] = 1.f / (1.f + __expf(-(red[0] + fc2_b[0])));
}

extern "C" void kernel_launch(void* const* d_in, const int* in_sizes, int n_in,
                              void* d_out, int out_size, void* d_ws, size_t ws_size,
                              hipStream_t stream) {
    const float* x        = (const float*)d_in[0];
    const float* xyz_w    = (const float*)d_in[1];
    const float* xyz_b    = (const float*)d_in[2];
    const float* ohe_w    = (const float*)d_in[3];
    const float* ohe_b    = (const float*)d_in[4];
    const float* in_proj_w  = (const float*)d_in[5];
    const float* in_proj_b  = (const float*)d_in[6];
    const float* out_proj_w = (const float*)d_in[7];
    const float* out_proj_b = (const float*)d_in[8];
    const float* ln1_w    = (const float*)d_in[9];
    const float* ln1_b    = (const float*)d_in[10];
    const float* lin1_w   = (const float*)d_in[11];
    const float* lin1_b   = (const float*)d_in[12];
    const float* lin2_w   = (const float*)d_in[13];
    const float* lin2_b   = (const float*)d_in[14];
    const float* ln2_w    = (const float*)d_in[15];
    const float* ln2_b    = (const float*)d_in[16];
    const float* fc1_w    = (const float*)d_in[17];
    const float* fc1_b    = (const float*)d_in[18];
    const float* fc2_w    = (const float*)d_in[19];
    const float* fc2_b    = (const float*)d_in[20];
    float* outp = (float*)d_out;

    char* ws = (char*)d_ws;
    size_t off = 0;
    auto alloc = [&](size_t bytes) { void* p = ws + off; off += (bytes + 255) & ~255ULL; return p; };
    _Float16*  feat16 = (_Float16*)alloc((size_t)Bq * Nq * Dq * 2);
    _Float16*  h16    = (_Float16*)alloc((size_t)Bq * Nq * Dq * 2);
    _Float16*  abuf16 = (_Float16*)alloc((size_t)Bq * Nq * Dq * 2);
    _Float16*  pkb    = (_Float16*)alloc(3ull * 64 * Nq * 16 * 2);
    _Float16*  wb     = (_Float16*)alloc(393216ull * 2);
    int*       idx    = (int*)alloc((size_t)Bq * Nq * KNNq * 4);
    float*     part   = (float*)alloc(2048ull * Dq * 4);
    if (off > ws_size) return;

    const _Float16* wip16 = wb;
    const _Float16* wop16 = wb + 98304;
    const _Float16* wl116 = wb + 131072;
    const _Float16* wl216 = wb + 262144;

    int M = Bq * Nq;

    prep_kernel<<<16384 + 1536, 256, 0, stream>>>(x, xyz_w, xyz_b, ohe_w, ohe_b, feat16,
                                                  in_proj_w, out_proj_w, lin1_w, lin2_w, wb);
    knn_kernel<<<dim3(Nq / 32, Bq), 256, 0, stream>>>(x, idx);
    knn_attn_kernel<<<M / 4, 256, 0, stream>>>(feat16, idx, h16);

    for (int l = 0; l < Lq; l++) {
        hgemm_kernel<2><<<dim3(384 / 64, M / 64), 256, 0, stream>>>(
            h16, wip16 + (size_t)l * 384 * 128, in_proj_b + l * 384, pkb, M, 384, 128);
        flash8_kernel<<<dim3(Nq / 64, Bq * Hq), 256, 0, stream>>>(pkb, abuf16);
        hgemm_ln_kernel<<<M / 64, 256, 0, stream>>>(
            abuf16, wop16 + (size_t)l * 128 * 128, out_proj_b + l * 128,
            ln1_w + l * 128, ln1_b + l * 128, h16, 128);
        if (l == 0) {
            ffn_kernel<0><<<M / 64, 256, 0, stream>>>(
                h16, wl116, lin1_b, wl216, lin2_b, ln2_w, ln2_b, h16, part);
        } else {
            ffn_kernel<1><<<M / 64, 256, 0, stream>>>(
                h16, wl116 + (size_t)l * 512 * 128, lin1_b + l * 512,
                wl216 + (size_t)l * 128 * 512, lin2_b + l * 128,
                ln2_w + l * 128, ln2_b + l * 128, h16, part);
        }
    }

    head_kernel<<<Bq, 512, 0, stream>>>(part, fc1_w, fc1_b, fc2_w, fc2_b, outp);
}

// Round 16
// 1111.362 us; speedup vs baseline: 1.0516x; 1.0516x over previous
//
#include <hip/hip_runtime.h>

#define Bq 8
#define Nq 4096
#define Dq 128
#define Hq 8
#define FFq 512
#define KNNq 16
#define Lq 2
#define DHq 16
#define EPSq 1e-5f

typedef _Float16 half4 __attribute__((ext_vector_type(4)));
typedef _Float16 half2t __attribute__((ext_vector_type(2)));
typedef float v4f __attribute__((ext_vector_type(4)));

static __device__ __forceinline__ half2t pkrtz(float a, float b) {
    return __builtin_bit_cast(half2t, __builtin_amdgcn_cvt_pkrtz(a, b));
}

// ---------------- fused prep: feat (f16) + weight fp32->f16 conversion ----------------
__global__ __launch_bounds__(256) void prep_kernel(const float* __restrict__ x,
                                                   const float* __restrict__ xyz_w,
                                                   const float* __restrict__ xyz_b,
                                                   const float* __restrict__ ohe_w,
                                                   const float* __restrict__ ohe_b,
                                                   _Float16* __restrict__ feat16,
                                                   const float* __restrict__ ipw,
                                                   const float* __restrict__ opw,
                                                   const float* __restrict__ l1w,
                                                   const float* __restrict__ l2w,
                                                   _Float16* __restrict__ wb) {
    int bid = blockIdx.x;
    if (bid < 16384) {
        int i = bid * 256 + threadIdx.x;
        int d = i & 127;
        int t = i >> 7;
        const float* xr = x + (size_t)t * 8;
        float s = xyz_b[d] + ohe_b[d];
        s += xr[0] * xyz_w[d * 3 + 0] + xr[1] * xyz_w[d * 3 + 1] + xr[2] * xyz_w[d * 3 + 2];
        s += xr[3] * ohe_w[d * 5 + 0] + xr[4] * ohe_w[d * 5 + 1] + xr[5] * ohe_w[d * 5 + 2]
           + xr[6] * ohe_w[d * 5 + 3] + xr[7] * ohe_w[d * 5 + 4];
        feat16[i] = (_Float16)s;
    } else {
        int i = (bid - 16384) * 256 + threadIdx.x;
        float v;
        if (i < 98304) v = ipw[i];
        else if (i < 131072) v = opw[i - 98304];
        else if (i < 262144) v = l1w[i - 131072];
        else v = l2w[i - 262144];
        wb[i] = (_Float16)v;
    }
}

// ---------------- KNN top-16 v6: dual chains, 48 KB LDS (3 blocks/CU), md aliased (R14 champ) ----------------
__global__ __launch_bounds__(256) void knn_kernel(const float* __restrict__ x, int* __restrict__ idx) {
    __shared__ __attribute__((aligned(16))) float sx[Nq];
    __shared__ __attribute__((aligned(16))) float sy[Nq];
    __shared__ __attribute__((aligned(16))) float sz[Nq];
    unsigned int (*md)[17] = (unsigned int (*)[17])sx;
    int b = blockIdx.y;
    int tid = threadIdx.x;
    for (int p = tid; p < Nq; p += 256) {
        const float* xr = x + ((size_t)b * Nq + p) * 8;
        sx[p] = xr[0]; sy[p] = xr[1]; sz[p] = xr[2];
    }
    __syncthreads();
    int qi = tid >> 3;
    int part = tid & 7;
    int n = blockIdx.x * 32 + qi;
    float qx = sx[n], qy = sy[n], qz = sz[n];
    unsigned int bdA[KNNq], bdB[KNNq];
#pragma unroll
    for (int i = 0; i < KNNq; i++) { bdA[i] = 0xFFFFFFFFu; bdB[i] = 0xFFFFFFFFu; }
    int j0 = part * 512;
    int rot = part;
    for (int jj = 0; jj < 256; jj++) {
        int j1 = j0 + ((jj + rot) & 511);
        int j2 = j0 + ((jj + 256 + rot) & 511);
        float p1x = sx[j1], p1y = sy[j1], p1z = sz[j1];
        float p2x = sx[j2], p2y = sy[j2], p2z = sz[j2];
        float dx1 = qx - p1x, dy1 = qy - p1y, dz1 = qz - p1z;
        float dx2 = qx - p2x, dy2 = qy - p2y, dz2 = qz - p2z;
        float d21 = fmaf(dx1, dx1, fmaf(dy1, dy1, dz1 * dz1));
        float d22 = fmaf(dx2, dx2, fmaf(dy2, dy2, dz2 * dz2));
        unsigned int k1 = (__float_as_uint(d21) & 0xFFFFF000u) | (unsigned int)j1;
        unsigned int k2 = (__float_as_uint(d22) & 0xFFFFF000u) | (unsigned int)j2;
        k1 = (j1 == n) ? 0xFFFFFFFFu : k1;
        k2 = (j2 == n) ? 0xFFFFFFFFu : k2;
#pragma unroll
        for (int i = 0; i < KNNq; i++) {
            unsigned int loA = bdA[i] < k1 ? bdA[i] : k1;
            unsigned int hiA = bdA[i] < k1 ? k1 : bdA[i];
            bdA[i] = loA; k1 = hiA;
            unsigned int loB = bdB[i] < k2 ? bdB[i] : k2;
            unsigned int hiB = bdB[i] < k2 ? k2 : bdB[i];
            bdB[i] = loB; k2 = hiB;
        }
    }
#pragma unroll
    for (int t = 0; t < KNNq; t++) {
        unsigned int key = bdB[t];
#pragma unroll
        for (int i = 0; i < KNNq; i++) {
            unsigned int lo = bdA[i] < key ? bdA[i] : key;
            unsigned int hi = bdA[i] < key ? key : bdA[i];
            bdA[i] = lo; key = hi;
        }
    }
    __syncthreads();
#pragma unroll
    for (int i = 0; i < KNNq; i++) md[tid][i] = bdA[i];
    __syncthreads();
    if (part == 0) {
        unsigned int pall = 0;
        int* op = idx + ((size_t)b * Nq + n) * KNNq;
        int base_row = qi * 8;
#pragma unroll
        for (int s = 0; s < KNNq; s++) {
            unsigned int best = 0xFFFFFFFFu; int bp = 0;
#pragma unroll
            for (int p2 = 0; p2 < 8; p2++) {
                unsigned int ptr = (pall >> (p2 * 4)) & 15u;
                unsigned int v = md[base_row + p2][ptr];
                if (v < best) { best = v; bp = p2; }
            }
            op[s] = (int)(best & 4095u);
            pall += (1u << (bp * 4));
        }
    }
}

// ---------------- KNN attention: f16 gathers, f32 math, emits h16 only ----------------
__global__ __launch_bounds__(256, 4) void knn_attn_kernel(const _Float16* __restrict__ feat16,
                                                          const int* __restrict__ idx,
                                                          _Float16* __restrict__ h16) {
    int wave = threadIdx.x >> 6;
    int lane = threadIdx.x & 63;
    int token = blockIdx.x * 4 + wave;
    int b = token >> 12;
    half2t fh = ((const half2t*)(feat16 + (size_t)token * Dq))[lane];
    float2 f = make_float2((float)fh[0], (float)fh[1]);
    const int* ip = idx + (size_t)token * KNNq;
    int jj[KNNq];
#pragma unroll
    for (int k = 0; k < KNNq; k++) jj[k] = ip[k];
    float2 g[KNNq];
#pragma unroll
    for (int k = 0; k < KNNq; k++) {
        half2t gh = ((const half2t*)(feat16 + (((size_t)b << 12) + jj[k]) * Dq))[lane];
        g[k] = make_float2((float)gh[0], (float)gh[1]);
    }
    float sc[KNNq];
#pragma unroll
    for (int k = 0; k < KNNq; k++) {
        float p = f.x * g[k].x + f.y * g[k].y;
#pragma unroll
        for (int m = 1; m < 64; m <<= 1) p += __shfl_xor(p, m);
        sc[k] = p * 0.088388347648318447f; // 1/sqrt(128)
    }
    float mx = sc[0];
#pragma unroll
    for (int k = 1; k < KNNq; k++) mx = fmaxf(mx, sc[k]);
    float sum = 0.f;
#pragma unroll
    for (int k = 0; k < KNNq; k++) { sc[k] = __expf(sc[k] - mx); sum += sc[k]; }
    float inv = 1.f / sum;
    float o0 = 0.f, o1 = 0.f;
#pragma unroll
    for (int k = 0; k < KNNq; k++) { o0 += sc[k] * g[k].x; o1 += sc[k] * g[k].y; }
    ((half2t*)(h16 + (size_t)token * Dq))[lane] = pkrtz(o0 * inv, o1 * inv);
}

// ---------------- f16 MFMA GEMM, LDS-free ----------------
// MODE 2: qkv pack — Q (pre-scaled by 0.25*log2e) and K to pk[sel][bh][n][16],
// V TRANSPOSED to slot2 as Vt[bh][d][n].
template <int MODE>
__global__ __launch_bounds__(256) void hgemm_kernel(const _Float16* __restrict__ A,
                                                    const _Float16* __restrict__ W,
                                                    const float* __restrict__ bias,
                                                    void* __restrict__ Cout,
                                                    int M, int Nc, int K) {
    int tid = threadIdx.x;
    int lane = tid & 63, w = tid >> 6;
    int l15 = lane & 15, l4 = lane >> 4;
    int m0 = blockIdx.y * 64 + w * 16;
    int n0 = blockIdx.x * 64;
    const _Float16* Ap = A + (size_t)(m0 + l15) * K + l4 * 4;
    const _Float16* Wp = W + (size_t)(n0 + l15) * K + l4 * 4;
    v4f acc[4] = {{0.f, 0.f, 0.f, 0.f}, {0.f, 0.f, 0.f, 0.f}, {0.f, 0.f, 0.f, 0.f}, {0.f, 0.f, 0.f, 0.f}};
    for (int ks = 0; ks < K; ks += 16) {
        half4 af = *(const half4*)(Ap + ks);
#pragma unroll
        for (int nt = 0; nt < 4; nt++) {
            half4 wf = *(const half4*)(Wp + (size_t)nt * 16 * K + ks);
            acc[nt] = __builtin_amdgcn_mfma_f32_16x16x16f16(wf, af, acc[nt], 0, 0, 0);
        }
    }
    int m = m0 + l15;
#pragma unroll
    for (int nt = 0; nt < 4; nt++) {
        int nb = n0 + nt * 16 + l4 * 4;
        float4 bv = *(const float4*)(bias + nb);
        float v0 = acc[nt][0] + bv.x, v1 = acc[nt][1] + bv.y;
        float v2 = acc[nt][2] + bv.z, v3 = acc[nt][3] + bv.w;
        int n_base = n0 + nt * 16;
        int sel = n_base >> 7;
        if (MODE == 2 && sel == 0) {
            v0 *= 0.36067376f; v1 *= 0.36067376f; v2 *= 0.36067376f; v3 *= 0.36067376f;
        }
        half2t lo = pkrtz(v0, v1);
        half2t hi = pkrtz(v2, v3);
        half4 hv; hv[0] = lo[0]; hv[1] = lo[1]; hv[2] = hi[0]; hv[3] = hi[1];
        if (sel < 2) {
            int hh = (n_base >> 4) & 7;
            size_t base = (size_t)sel * (64ull * Nq * 16)
                        + ((size_t)((m >> 12) * 8 + hh)) * (Nq * 16)
                        + (size_t)(m & 4095) * 16 + l4 * 4;
            *(half4*)((_Float16*)Cout + base) = hv;
        } else {
            int hh = (n_base >> 4) & 7;
            size_t vb = 2ull * 64 * Nq * 16
                      + ((size_t)((m >> 12) * 8 + hh)) * (16 * Nq)
                      + (size_t)(m & 4095);
            _Float16* vp = (_Float16*)Cout + vb + (size_t)(l4 * 4) * Nq;
            vp[0 * Nq] = hv[0]; vp[1 * Nq] = hv[1]; vp[2 * Nq] = hv[2]; vp[3 * Nq] = hv[3];
        }
    }
}

// ---------------- flash v9 = flash5 exactly (R7-measured 202 µs best): 64-key tiles,
// K+V LDS single-barrier dbuf, scalar lsum ----------------
__global__ __launch_bounds__(256) void flash9_kernel(const _Float16* __restrict__ pk,
                                                     _Float16* __restrict__ out16) {
    __shared__ _Float16 Ks[2][64 * 20];   // K rows, padded pitch 20
    __shared__ _Float16 Vs[2][16 * 66];   // V^T rows, padded pitch 66
    int tid = threadIdx.x;
    int lane = tid & 63, w = tid >> 6;
    int bh = blockIdx.y;
    const _Float16* Qb = pk + (size_t)bh * (Nq * 16);
    const _Float16* Kb = pk + (size_t)(64 + bh) * (Nq * 16);
    const _Float16* Vt = pk + 2ull * 64 * Nq * 16 + (size_t)bh * (16 * Nq);
    int q0 = blockIdx.x * 64 + w * 16;
    int l15 = lane & 15, l4 = lane >> 4;

    // Q fragment (B-operand); score scale folded by producer
    half4 qf = *(const half4*)(Qb + (size_t)(q0 + l15) * 16 + l4 * 4);

    int sr = tid >> 2, sc = tid & 3;        // K staging coords
    int vd = tid >> 4, vj = (tid & 15) * 4; // V staging coords
    const _Float16* Kg = Kb + (size_t)sr * 16 + sc * 4;
    const _Float16* Vg = Vt + (size_t)vd * Nq + vj;

    *(half4*)(Ks[0] + sr * 20 + sc * 4) = *(const half4*)(Kg);
    *(half4*)(Vs[0] + vd * 66 + vj) = *(const half4*)(Vg);
    __syncthreads();

    v4f o = {0.f, 0.f, 0.f, 0.f};
    float lsum = 0.f;

    for (int kt = 0; kt < Nq / 64; kt++) {
        int cur = kt & 1, nxt = cur ^ 1;
        if (kt < Nq / 64 - 1) {
            *(half4*)(Ks[nxt] + sr * 20 + sc * 4) = *(const half4*)(Kg + (size_t)(kt + 1) * 64 * 16);
            *(half4*)(Vs[nxt] + vd * 66 + vj) = *(const half4*)(Vg + (kt + 1) * 64);
        }
        // S^T = K @ Q^T
        v4f S[4];
#pragma unroll
        for (int g = 0; g < 4; g++) {
            half4 kf = *(const half4*)(Ks[cur] + (g * 16 + l15) * 20 + l4 * 4);
            S[g] = __builtin_amdgcn_mfma_f32_16x16x16f16(kf, qf, (v4f){0.f, 0.f, 0.f, 0.f}, 0, 0, 0);
        }
        // P = 2^S (no-max softmax, bounded scores); scalar lsum (measured best, R7 vs R14)
        half4 P[4];
#pragma unroll
        for (int g = 0; g < 4; g++) {
            float p0 = __builtin_amdgcn_exp2f(S[g][0]);
            float p1 = __builtin_amdgcn_exp2f(S[g][1]);
            float p2 = __builtin_amdgcn_exp2f(S[g][2]);
            float p3 = __builtin_amdgcn_exp2f(S[g][3]);
            lsum += (p0 + p1) + (p2 + p3);
            half2t lo = pkrtz(p0, p1);
            half2t hi = pkrtz(p2, p3);
            P[g][0] = lo[0]; P[g][1] = lo[1]; P[g][2] = hi[0]; P[g][3] = hi[1];
        }
        // O^T += V^T @ P^T
#pragma unroll
        for (int g = 0; g < 4; g++) {
            half4 vf = *(const half4*)(Vs[cur] + l15 * 66 + g * 16 + l4 * 4);
            o = __builtin_amdgcn_mfma_f32_16x16x16f16(vf, P[g], o, 0, 0, 0);
        }
        __syncthreads();
    }
    lsum += __shfl_xor(lsum, 16);
    lsum += __shfl_xor(lsum, 32);
    float inv = 1.f / lsum;
    int row = q0 + l15;
    int b = bh >> 3, hh = bh & 7;
    half2t lo = pkrtz(o[0] * inv, o[1] * inv);
    half2t hi = pkrtz(o[2] * inv, o[3] * inv);
    half4 hv; hv[0] = lo[0]; hv[1] = lo[1]; hv[2] = hi[0]; hv[3] = hi[1];
    *(half4*)(out16 + ((size_t)(b * Nq + row)) * Dq + hh * 16 + l4 * 4) = hv;
}

// ---------------- fused GEMM(Nc=128) + residual(h16) + LayerNorm -> h16 ----------------
__global__ __launch_bounds__(256) void hgemm_ln_kernel(const _Float16* __restrict__ A,
                                                       const _Float16* __restrict__ W,
                                                       const float* __restrict__ bias,
                                                       const float* __restrict__ lnw,
                                                       const float* __restrict__ lnb,
                                                       _Float16* __restrict__ h16,
                                                       int K) {
    int tid = threadIdx.x;
    int lane = tid & 63, w = tid >> 6;
    int l15 = lane & 15, l4 = lane >> 4;
    int m0 = blockIdx.x * 64 + w * 16;
    const _Float16* Ap = A + (size_t)(m0 + l15) * K + l4 * 4;
    const _Float16* Wp = W + (size_t)l15 * K + l4 * 4;
    v4f acc[8] = {};
    for (int ks = 0; ks < K; ks += 16) {
        half4 af = *(const half4*)(Ap + ks);
#pragma unroll
        for (int nt = 0; nt < 8; nt++) {
            half4 wf = *(const half4*)(Wp + (size_t)nt * 16 * K + ks);
            acc[nt] = __builtin_amdgcn_mfma_f32_16x16x16f16(wf, af, acc[nt], 0, 0, 0);
        }
    }
    int m = m0 + l15;
    float x[8][4];
    float psum = 0.f;
#pragma unroll
    for (int nt = 0; nt < 8; nt++) {
        int nb = nt * 16 + l4 * 4;
        float4 bv = *(const float4*)(bias + nb);
        half4 rv = *(const half4*)(h16 + (size_t)m * Dq + nb);
        x[nt][0] = acc[nt][0] + bv.x + (float)rv[0];
        x[nt][1] = acc[nt][1] + bv.y + (float)rv[1];
        x[nt][2] = acc[nt][2] + bv.z + (float)rv[2];
        x[nt][3] = acc[nt][3] + bv.w + (float)rv[3];
        psum += (x[nt][0] + x[nt][1]) + (x[nt][2] + x[nt][3]);
    }
    psum += __shfl_xor(psum, 16);
    psum += __shfl_xor(psum, 32);
    float mean = psum * (1.f / 128.f);
    float vsum = 0.f;
#pragma unroll
    for (int nt = 0; nt < 8; nt++)
#pragma unroll
        for (int r = 0; r < 4; r++) {
            x[nt][r] -= mean;
            vsum += x[nt][r] * x[nt][r];
        }
    vsum += __shfl_xor(vsum, 16);
    vsum += __shfl_xor(vsum, 32);
    float inv = rsqrtf(vsum * (1.f / 128.f) + EPSq);
#pragma unroll
    for (int nt = 0; nt < 8; nt++) {
        int nb = nt * 16 + l4 * 4;
        float4 wv = *(const float4*)(lnw + nb);
        float4 bb = *(const float4*)(lnb + nb);
        float y0 = x[nt][0] * inv * wv.x + bb.x;
        float y1 = x[nt][1] * inv * wv.y + bb.y;
        float y2 = x[nt][2] * inv * wv.z + bb.z;
        float y3 = x[nt][3] * inv * wv.w + bb.w;
        half2t lo = pkrtz(y0, y1);
        half2t hi = pkrtz(y2, y3);
        half4 hv2; hv2[0] = lo[0]; hv2[1] = lo[1]; hv2[2] = hi[0]; hv2[3] = hi[1];
        *(half4*)(h16 + (size_t)m * Dq + nb) = hv2;
    }
}

// ---------------- fused FFN (+ LN). LAST=1: emit per-wave column partial sums for pooling ----------------
template <int LAST>
__global__ __launch_bounds__(256) void ffn_kernel(const _Float16* __restrict__ h16in,
                                                  const _Float16* __restrict__ W1,
                                                  const float* __restrict__ b1,
                                                  const _Float16* __restrict__ W2,
                                                  const float* __restrict__ b2,
                                                  const float* __restrict__ lnw,
                                                  const float* __restrict__ lnb,
                                                  _Float16* __restrict__ h16,
                                                  float* __restrict__ part) {
    int tid = threadIdx.x;
    int lane = tid & 63, w = tid >> 6;
    int l15 = lane & 15, l4 = lane >> 4;
    int m0 = blockIdx.x * 64 + w * 16;
    int m = m0 + l15;
    const _Float16* Ap = h16in + (size_t)m * Dq + l4 * 4;
    half4 afr[8];
#pragma unroll
    for (int t = 0; t < 8; t++) afr[t] = *(const half4*)(Ap + t * 16);
    half4 mid[32];
#pragma unroll
    for (int c = 0; c < 8; c++) {
        v4f acc[4] = {};
#pragma unroll
        for (int t = 0; t < 8; t++) {
#pragma unroll
            for (int nt = 0; nt < 4; nt++) {
                half4 wf = *(const half4*)(W1 + (size_t)(c * 64 + nt * 16 + l15) * 128 + t * 16 + l4 * 4);
                acc[nt] = __builtin_amdgcn_mfma_f32_16x16x16f16(wf, afr[t], acc[nt], 0, 0, 0);
            }
        }
#pragma unroll
        for (int nt = 0; nt < 4; nt++) {
            float4 bv = *(const float4*)(b1 + c * 64 + nt * 16 + l4 * 4);
            float v0 = fmaxf(acc[nt][0] + bv.x, 0.f);
            float v1 = fmaxf(acc[nt][1] + bv.y, 0.f);
            float v2 = fmaxf(acc[nt][2] + bv.z, 0.f);
            float v3 = fmaxf(acc[nt][3] + bv.w, 0.f);
            half2t lo = pkrtz(v0, v1), hi = pkrtz(v2, v3);
            half4 hv; hv[0] = lo[0]; hv[1] = lo[1]; hv[2] = hi[0]; hv[3] = hi[1];
            mid[c * 4 + nt] = hv;
        }
    }
    v4f acc8[8] = {};
#pragma unroll 4
    for (int t = 0; t < 32; t++) {
#pragma unroll
        for (int nt = 0; nt < 8; nt++) {
            half4 wf = *(const half4*)(W2 + (size_t)(nt * 16 + l15) * 512 + t * 16 + l4 * 4);
            acc8[nt] = __builtin_amdgcn_mfma_f32_16x16x16f16(wf, mid[t], acc8[nt], 0, 0, 0);
        }
    }
    float x[8][4];
    float psum = 0.f;
#pragma unroll
    for (int nt = 0; nt < 8; nt++) {
        int nb = nt * 16 + l4 * 4;
        float4 bv = *(const float4*)(b2 + nb);
        x[nt][0] = acc8[nt][0] + bv.x + (float)afr[nt][0];
        x[nt][1] = acc8[nt][1] + bv.y + (float)afr[nt][1];
        x[nt][2] = acc8[nt][2] + bv.z + (float)afr[nt][2];
        x[nt][3] = acc8[nt][3] + bv.w + (float)afr[nt][3];
        psum += (x[nt][0] + x[nt][1]) + (x[nt][2] + x[nt][3]);
    }
    psum += __shfl_xor(psum, 16);
    psum += __shfl_xor(psum, 32);
    float mean = psum * (1.f / 128.f);
    float vsum = 0.f;
#pragma unroll
    for (int nt = 0; nt < 8; nt++)
#pragma unroll
        for (int r = 0; r < 4; r++) {
            x[nt][r] -= mean;
            vsum += x[nt][r] * x[nt][r];
        }
    vsum += __shfl_xor(vsum, 16);
    vsum += __shfl_xor(vsum, 32);
    float inv = rsqrtf(vsum * (1.f / 128.f) + EPSq);
#pragma unroll
    for (int nt = 0; nt < 8; nt++) {
        int nb = nt * 16 + l4 * 4;
        float4 wv = *(const float4*)(lnw + nb);
        float4 bb = *(const float4*)(lnb + nb);
        x[nt][0] = x[nt][0] * inv * wv.x + bb.x;
        x[nt][1] = x[nt][1] * inv * wv.y + bb.y;
        x[nt][2] = x[nt][2] * inv * wv.z + bb.z;
        x[nt][3] = x[nt][3] * inv * wv.w + bb.w;
        if (!LAST) {
            half2t lo = pkrtz(x[nt][0], x[nt][1]);
            half2t hi = pkrtz(x[nt][2], x[nt][3]);
            half4 hv2; hv2[0] = lo[0]; hv2[1] = lo[1]; hv2[2] = hi[0]; hv2[3] = hi[1];
            *(half4*)(h16 + (size_t)m * Dq + nb) = hv2;
        }
    }
    if (LAST) {
#pragma unroll
        for (int nt = 0; nt < 8; nt++)
#pragma unroll
            for (int r = 0; r < 4; r++) {
                float v = x[nt][r];
                v += __shfl_xor(v, 1);
                v += __shfl_xor(v, 2);
                v += __shfl_xor(v, 4);
                v += __shfl_xor(v, 8);
                x[nt][r] = v;
            }
        if (l15 == 0) {
            float* pp = part + ((size_t)blockIdx.x * 4 + w) * Dq;
#pragma unroll
            for (int nt = 0; nt < 8; nt++)
#pragma unroll
                for (int r = 0; r < 4; r++)
                    pp[nt * 16 + l4 * 4 + r] = x[nt][r];
        }
    }
}

// ---------------- head: pooled = mean over N via 256 wave-partials; MLP + sigmoid ----------------
__global__ __launch_bounds__(512) void head_kernel(const float* __restrict__ part,
                                                   const float* __restrict__ fc1_w, const float* __restrict__ fc1_b,
                                                   const float* __restrict__ fc2_w, const float* __restrict__ fc2_b,
                                                   float* __restrict__ out) {
    __shared__ float psh[Dq];
    __shared__ float red[512];
    int b = blockIdx.x, f = threadIdx.x;
    if (f < Dq) {
        float s = 0.f;
        for (int c = 0; c < 256; c++) s += part[((size_t)b * 256 + c) * Dq + f];
        psh[f] = s * (1.f / 4096.f);
    }
    __syncthreads();
    const float* wr = fc1_w + (size_t)f * Dq;
    float s = fc1_b[f];
    for (int d = 0; d < Dq; d++) s += psh[d] * wr[d];
    red[f] = fmaxf(s, 0.f) * fc2_w[f];
    __syncthreads();
    for (int st = 256; st > 0; st >>= 1) {
        if (f < st) red[f] += red[f + st];
        __syncthreads();
    }
    if (f == 0) out[b] = 1.f / (1.f + __expf(-(red[0] + fc2_b[0])));
}

extern "C" void kernel_launch(void* const* d_in, const int* in_sizes, int n_in,
                              void* d_out, int out_size, void* d_ws, size_t ws_size,
                              hipStream_t stream) {
    const float* x        = (const float*)d_in[0];
    const float* xyz_w    = (const float*)d_in[1];
    const float* xyz_b    = (const float*)d_in[2];
    const float* ohe_w    = (const float*)d_in[3];
    const float* ohe_b    = (const float*)d_in[4];
    const float* in_proj_w  = (const float*)d_in[5];
    const float* in_proj_b  = (const float*)d_in[6];
    const float* out_proj_w = (const float*)d_in[7];
    const float* out_proj_b = (const float*)d_in[8];
    const float* ln1_w    = (const float*)d_in[9];
    const float* ln1_b    = (const float*)d_in[10];
    const float* lin1_w   = (const float*)d_in[11];
    const float* lin1_b   = (const float*)d_in[12];
    const float* lin2_w   = (const float*)d_in[13];
    const float* lin2_b   = (const float*)d_in[14];
    const float* ln2_w    = (const float*)d_in[15];
    const float* ln2_b    = (const float*)d_in[16];
    const float* fc1_w    = (const float*)d_in[17];
    const float* fc1_b    = (const float*)d_in[18];
    const float* fc2_w    = (const float*)d_in[19];
    const float* fc2_b    = (const float*)d_in[20];
    float* outp = (float*)d_out;

    char* ws = (char*)d_ws;
    size_t off = 0;
    auto alloc = [&](size_t bytes) { void* p = ws + off; off += (bytes + 255) & ~255ULL; return p; };
    _Float16*  feat16 = (_Float16*)alloc((size_t)Bq * Nq * Dq * 2);
    _Float16*  h16    = (_Float16*)alloc((size_t)Bq * Nq * Dq * 2);
    _Float16*  abuf16 = (_Float16*)alloc((size_t)Bq * Nq * Dq * 2);
    _Float16*  pkb    = (_Float16*)alloc(3ull * 64 * Nq * 16 * 2);
    _Float16*  wb     = (_Float16*)alloc(393216ull * 2);
    int*       idx    = (int*)alloc((size_t)Bq * Nq * KNNq * 4);
    float*     part   = (float*)alloc(2048ull * Dq * 4);
    if (off > ws_size) return;

    const _Float16* wip16 = wb;
    const _Float16* wop16 = wb + 98304;
    const _Float16* wl116 = wb + 131072;
    const _Float16* wl216 = wb + 262144;

    int M = Bq * Nq;

    prep_kernel<<<16384 + 1536, 256, 0, stream>>>(x, xyz_w, xyz_b, ohe_w, ohe_b, feat16,
                                                  in_proj_w, out_proj_w, lin1_w, lin2_w, wb);
    knn_kernel<<<dim3(Nq / 32, Bq), 256, 0, stream>>>(x, idx);
    knn_attn_kernel<<<M / 4, 256, 0, stream>>>(feat16, idx, h16);

    for (int l = 0; l < Lq; l++) {
        hgemm_kernel<2><<<dim3(384 / 64, M / 64), 256, 0, stream>>>(
            h16, wip16 + (size_t)l * 384 * 128, in_proj_b + l * 384, pkb, M, 384, 128);
        flash9_kernel<<<dim3(Nq / 64, Bq * Hq), 256, 0, stream>>>(pkb, abuf16);
        hgemm_ln_kernel<<<M / 64, 256, 0, stream>>>(
            abuf16, wop16 + (size_t)l * 128 * 128, out_proj_b + l * 128,
            ln1_w + l * 128, ln1_b + l * 128, h16, 128);
        if (l == 0) {
            ffn_kernel<0><<<M / 64, 256, 0, stream>>>(
                h16, wl116, lin1_b, wl216, lin2_b, ln2_w, ln2_b, h16, part);
        } else {
            ffn_kernel<1><<<M / 64, 256, 0, stream>>>(
                h16, wl116 + (size_t)l * 512 * 128, lin1_b + l * 512,
                wl216 + (size_t)l * 128 * 512, lin2_b + l * 128,
                ln2_w + l * 128, ln2_b + l * 128, h16, part);
        }
    }

    head_kernel<<<Bq, 512, 0, stream>>>(part, fc1_w, fc1_b, fc2_w, fc2_b, outp);
}

// Round 17
// 1100.831 us; speedup vs baseline: 1.0616x; 1.0096x over previous
//
#include <hip/hip_runtime.h>

#define Bq 8
#define Nq 4096
#define Dq 128
#define Hq 8
#define FFq 512
#define KNNq 16
#define Lq 2
#define DHq 16
#define EPSq 1e-5f

typedef _Float16 half4 __attribute__((ext_vector_type(4)));
typedef _Float16 half2t __attribute__((ext_vector_type(2)));
typedef float v4f __attribute__((ext_vector_type(4)));

static __device__ __forceinline__ half2t pkrtz(float a, float b) {
    return __builtin_bit_cast(half2t, __builtin_amdgcn_cvt_pkrtz(a, b));
}

// ---------------- fused prep: feat (f16) + weight fp32->f16 conversion ----------------
__global__ __launch_bounds__(256) void prep_kernel(const float* __restrict__ x,
                                                   const float* __restrict__ xyz_w,
                                                   const float* __restrict__ xyz_b,
                                                   const float* __restrict__ ohe_w,
                                                   const float* __restrict__ ohe_b,
                                                   _Float16* __restrict__ feat16,
                                                   const float* __restrict__ ipw,
                                                   const float* __restrict__ opw,
                                                   const float* __restrict__ l1w,
                                                   const float* __restrict__ l2w,
                                                   _Float16* __restrict__ wb) {
    int bid = blockIdx.x;
    if (bid < 16384) {
        int i = bid * 256 + threadIdx.x;
        int d = i & 127;
        int t = i >> 7;
        const float* xr = x + (size_t)t * 8;
        float s = xyz_b[d] + ohe_b[d];
        s += xr[0] * xyz_w[d * 3 + 0] + xr[1] * xyz_w[d * 3 + 1] + xr[2] * xyz_w[d * 3 + 2];
        s += xr[3] * ohe_w[d * 5 + 0] + xr[4] * ohe_w[d * 5 + 1] + xr[5] * ohe_w[d * 5 + 2]
           + xr[6] * ohe_w[d * 5 + 3] + xr[7] * ohe_w[d * 5 + 4];
        feat16[i] = (_Float16)s;
    } else {
        int i = (bid - 16384) * 256 + threadIdx.x;
        float v;
        if (i < 98304) v = ipw[i];
        else if (i < 131072) v = opw[i - 98304];
        else if (i < 262144) v = l1w[i - 131072];
        else v = l2w[i - 262144];
        wb[i] = (_Float16)v;
    }
}

// ---------------- KNN top-16 v7: v6 algorithm, 512-thread blocks (64 queries share 48 KB stage) ----------------
// 2 blocks/CU resident -> 16 waves/CU = 4 waves/SIMD (vs 3), same LDS data amortized over 2x queries.
__global__ __launch_bounds__(512) void knn_kernel(const float* __restrict__ x, int* __restrict__ idx) {
    __shared__ __attribute__((aligned(16))) float sx[Nq];  // 16 KB
    __shared__ __attribute__((aligned(16))) float sy[Nq];  // 16 KB
    __shared__ __attribute__((aligned(16))) float sz[Nq];  // 16 KB -> 48 KB
    unsigned int (*md)[17] = (unsigned int (*)[17])sx;     // 512*17*4 = 34 KB, aliased (dead after scan)
    int b = blockIdx.y;
    int tid = threadIdx.x;
    for (int p = tid; p < Nq; p += 512) {
        const float* xr = x + ((size_t)b * Nq + p) * 8;
        sx[p] = xr[0]; sy[p] = xr[1]; sz[p] = xr[2];
    }
    __syncthreads();
    int qi = tid >> 3;   // 0..63 local query
    int part = tid & 7;
    int n = blockIdx.x * 64 + qi;
    float qx = sx[n], qy = sy[n], qz = sz[n];
    unsigned int bdA[KNNq], bdB[KNNq];
#pragma unroll
    for (int i = 0; i < KNNq; i++) { bdA[i] = 0xFFFFFFFFu; bdB[i] = 0xFFFFFFFFu; }
    int j0 = part * 512;
    int rot = part; // bank offset 4*part % 32: partitions disjoint, same-part lanes broadcast
    for (int jj = 0; jj < 256; jj++) {
        int j1 = j0 + ((jj + rot) & 511);
        int j2 = j0 + ((jj + 256 + rot) & 511);
        float p1x = sx[j1], p1y = sy[j1], p1z = sz[j1];
        float p2x = sx[j2], p2y = sy[j2], p2z = sz[j2];
        float dx1 = qx - p1x, dy1 = qy - p1y, dz1 = qz - p1z;
        float dx2 = qx - p2x, dy2 = qy - p2y, dz2 = qz - p2z;
        float d21 = fmaf(dx1, dx1, fmaf(dy1, dy1, dz1 * dz1));
        float d22 = fmaf(dx2, dx2, fmaf(dy2, dy2, dz2 * dz2));
        unsigned int k1 = (__float_as_uint(d21) & 0xFFFFF000u) | (unsigned int)j1;
        unsigned int k2 = (__float_as_uint(d22) & 0xFFFFF000u) | (unsigned int)j2;
        k1 = (j1 == n) ? 0xFFFFFFFFu : k1;
        k2 = (j2 == n) ? 0xFFFFFFFFu : k2;
#pragma unroll
        for (int i = 0; i < KNNq; i++) {   // two INDEPENDENT chains -> 2x ILP
            unsigned int loA = bdA[i] < k1 ? bdA[i] : k1;
            unsigned int hiA = bdA[i] < k1 ? k1 : bdA[i];
            bdA[i] = loA; k1 = hiA;
            unsigned int loB = bdB[i] < k2 ? bdB[i] : k2;
            unsigned int hiB = bdB[i] < k2 ? k2 : bdB[i];
            bdB[i] = loB; k2 = hiB;
        }
    }
    // merge chain B into chain A (once; branchless)
#pragma unroll
    for (int t = 0; t < KNNq; t++) {
        unsigned int key = bdB[t];
#pragma unroll
        for (int i = 0; i < KNNq; i++) {
            unsigned int lo = bdA[i] < key ? bdA[i] : key;
            unsigned int hi = bdA[i] < key ? key : bdA[i];
            bdA[i] = lo; key = hi;
        }
    }
    __syncthreads(); // all waves done scanning before md overwrites the scan buffer
#pragma unroll
    for (int i = 0; i < KNNq; i++) md[tid][i] = bdA[i];
    __syncthreads();
    if (part == 0) {
        unsigned int pall = 0;
        int* op = idx + ((size_t)b * Nq + n) * KNNq;
        int base_row = qi * 8;
#pragma unroll
        for (int s = 0; s < KNNq; s++) {
            unsigned int best = 0xFFFFFFFFu; int bp = 0;
#pragma unroll
            for (int p2 = 0; p2 < 8; p2++) {
                unsigned int ptr = (pall >> (p2 * 4)) & 15u;
                unsigned int v = md[base_row + p2][ptr];
                if (v < best) { best = v; bp = p2; }
            }
            op[s] = (int)(best & 4095u);
            pall += (1u << (bp * 4));
        }
    }
}

// ---------------- KNN attention: f16 gathers, f32 math, emits h16 only ----------------
__global__ __launch_bounds__(256, 4) void knn_attn_kernel(const _Float16* __restrict__ feat16,
                                                          const int* __restrict__ idx,
                                                          _Float16* __restrict__ h16) {
    int wave = threadIdx.x >> 6;
    int lane = threadIdx.x & 63;
    int token = blockIdx.x * 4 + wave;
    int b = token >> 12;
    half2t fh = ((const half2t*)(feat16 + (size_t)token * Dq))[lane];
    float2 f = make_float2((float)fh[0], (float)fh[1]);
    const int* ip = idx + (size_t)token * KNNq;
    int jj[KNNq];
#pragma unroll
    for (int k = 0; k < KNNq; k++) jj[k] = ip[k];
    float2 g[KNNq];
#pragma unroll
    for (int k = 0; k < KNNq; k++) {
        half2t gh = ((const half2t*)(feat16 + (((size_t)b << 12) + jj[k]) * Dq))[lane];
        g[k] = make_float2((float)gh[0], (float)gh[1]);
    }
    float sc[KNNq];
#pragma unroll
    for (int k = 0; k < KNNq; k++) {
        float p = f.x * g[k].x + f.y * g[k].y;
#pragma unroll
        for (int m = 1; m < 64; m <<= 1) p += __shfl_xor(p, m);
        sc[k] = p * 0.088388347648318447f; // 1/sqrt(128)
    }
    float mx = sc[0];
#pragma unroll
    for (int k = 1; k < KNNq; k++) mx = fmaxf(mx, sc[k]);
    float sum = 0.f;
#pragma unroll
    for (int k = 0; k < KNNq; k++) { sc[k] = __expf(sc[k] - mx); sum += sc[k]; }
    float inv = 1.f / sum;
    float o0 = 0.f, o1 = 0.f;
#pragma unroll
    for (int k = 0; k < KNNq; k++) { o0 += sc[k] * g[k].x; o1 += sc[k] * g[k].y; }
    ((half2t*)(h16 + (size_t)token * Dq))[lane] = pkrtz(o0 * inv, o1 * inv);
}

// ---------------- f16 MFMA GEMM, LDS-free ----------------
// MODE 2: qkv pack — Q (pre-scaled by 0.25*log2e) and K to pk[sel][bh][n][16],
// V TRANSPOSED to slot2 as Vt[bh][d][n].
template <int MODE>
__global__ __launch_bounds__(256) void hgemm_kernel(const _Float16* __restrict__ A,
                                                    const _Float16* __restrict__ W,
                                                    const float* __restrict__ bias,
                                                    void* __restrict__ Cout,
                                                    int M, int Nc, int K) {
    int tid = threadIdx.x;
    int lane = tid & 63, w = tid >> 6;
    int l15 = lane & 15, l4 = lane >> 4;
    int m0 = blockIdx.y * 64 + w * 16;
    int n0 = blockIdx.x * 64;
    const _Float16* Ap = A + (size_t)(m0 + l15) * K + l4 * 4;
    const _Float16* Wp = W + (size_t)(n0 + l15) * K + l4 * 4;
    v4f acc[4] = {{0.f, 0.f, 0.f, 0.f}, {0.f, 0.f, 0.f, 0.f}, {0.f, 0.f, 0.f, 0.f}, {0.f, 0.f, 0.f, 0.f}};
    for (int ks = 0; ks < K; ks += 16) {
        half4 af = *(const half4*)(Ap + ks);
#pragma unroll
        for (int nt = 0; nt < 4; nt++) {
            half4 wf = *(const half4*)(Wp + (size_t)nt * 16 * K + ks);
            acc[nt] = __builtin_amdgcn_mfma_f32_16x16x16f16(wf, af, acc[nt], 0, 0, 0);
        }
    }
    int m = m0 + l15;
#pragma unroll
    for (int nt = 0; nt < 4; nt++) {
        int nb = n0 + nt * 16 + l4 * 4;
        float4 bv = *(const float4*)(bias + nb);
        float v0 = acc[nt][0] + bv.x, v1 = acc[nt][1] + bv.y;
        float v2 = acc[nt][2] + bv.z, v3 = acc[nt][3] + bv.w;
        int n_base = n0 + nt * 16;
        int sel = n_base >> 7;
        if (MODE == 2 && sel == 0) {
            v0 *= 0.36067376f; v1 *= 0.36067376f; v2 *= 0.36067376f; v3 *= 0.36067376f;
        }
        half2t lo = pkrtz(v0, v1);
        half2t hi = pkrtz(v2, v3);
        half4 hv; hv[0] = lo[0]; hv[1] = lo[1]; hv[2] = hi[0]; hv[3] = hi[1];
        if (sel < 2) {
            int hh = (n_base >> 4) & 7;
            size_t base = (size_t)sel * (64ull * Nq * 16)
                        + ((size_t)((m >> 12) * 8 + hh)) * (Nq * 16)
                        + (size_t)(m & 4095) * 16 + l4 * 4;
            *(half4*)((_Float16*)Cout + base) = hv;
        } else {
            int hh = (n_base >> 4) & 7;
            size_t vb = 2ull * 64 * Nq * 16
                      + ((size_t)((m >> 12) * 8 + hh)) * (16 * Nq)
                      + (size_t)(m & 4095);
            _Float16* vp = (_Float16*)Cout + vb + (size_t)(l4 * 4) * Nq;
            vp[0 * Nq] = hv[0]; vp[1 * Nq] = hv[1]; vp[2 * Nq] = hv[2]; vp[3 * Nq] = hv[3];
        }
    }
}

// ---------------- flash v9 = flash5 (R7/R16-measured best): 64-key tiles, K+V LDS dbuf, scalar lsum ----------------
__global__ __launch_bounds__(256) void flash9_kernel(const _Float16* __restrict__ pk,
                                                     _Float16* __restrict__ out16) {
    __shared__ _Float16 Ks[2][64 * 20];
    __shared__ _Float16 Vs[2][16 * 66];
    int tid = threadIdx.x;
    int lane = tid & 63, w = tid >> 6;
    int bh = blockIdx.y;
    const _Float16* Qb = pk + (size_t)bh * (Nq * 16);
    const _Float16* Kb = pk + (size_t)(64 + bh) * (Nq * 16);
    const _Float16* Vt = pk + 2ull * 64 * Nq * 16 + (size_t)bh * (16 * Nq);
    int q0 = blockIdx.x * 64 + w * 16;
    int l15 = lane & 15, l4 = lane >> 4;

    half4 qf = *(const half4*)(Qb + (size_t)(q0 + l15) * 16 + l4 * 4);

    int sr = tid >> 2, sc = tid & 3;
    int vd = tid >> 4, vj = (tid & 15) * 4;
    const _Float16* Kg = Kb + (size_t)sr * 16 + sc * 4;
    const _Float16* Vg = Vt + (size_t)vd * Nq + vj;

    *(half4*)(Ks[0] + sr * 20 + sc * 4) = *(const half4*)(Kg);
    *(half4*)(Vs[0] + vd * 66 + vj) = *(const half4*)(Vg);
    __syncthreads();

    v4f o = {0.f, 0.f, 0.f, 0.f};
    float lsum = 0.f;

    for (int kt = 0; kt < Nq / 64; kt++) {
        int cur = kt & 1, nxt = cur ^ 1;
        if (kt < Nq / 64 - 1) {
            *(half4*)(Ks[nxt] + sr * 20 + sc * 4) = *(const half4*)(Kg + (size_t)(kt + 1) * 64 * 16);
            *(half4*)(Vs[nxt] + vd * 66 + vj) = *(const half4*)(Vg + (kt + 1) * 64);
        }
        v4f S[4];
#pragma unroll
        for (int g = 0; g < 4; g++) {
            half4 kf = *(const half4*)(Ks[cur] + (g * 16 + l15) * 20 + l4 * 4);
            S[g] = __builtin_amdgcn_mfma_f32_16x16x16f16(kf, qf, (v4f){0.f, 0.f, 0.f, 0.f}, 0, 0, 0);
        }
        half4 P[4];
#pragma unroll
        for (int g = 0; g < 4; g++) {
            float p0 = __builtin_amdgcn_exp2f(S[g][0]);
            float p1 = __builtin_amdgcn_exp2f(S[g][1]);
            float p2 = __builtin_amdgcn_exp2f(S[g][2]);
            float p3 = __builtin_amdgcn_exp2f(S[g][3]);
            lsum += (p0 + p1) + (p2 + p3);
            half2t lo = pkrtz(p0, p1);
            half2t hi = pkrtz(p2, p3);
            P[g][0] = lo[0]; P[g][1] = lo[1]; P[g][2] = hi[0]; P[g][3] = hi[1];
        }
#pragma unroll
        for (int g = 0; g < 4; g++) {
            half4 vf = *(const half4*)(Vs[cur] + l15 * 66 + g * 16 + l4 * 4);
            o = __builtin_amdgcn_mfma_f32_16x16x16f16(vf, P[g], o, 0, 0, 0);
        }
        __syncthreads();
    }
    lsum += __shfl_xor(lsum, 16);
    lsum += __shfl_xor(lsum, 32);
    float inv = 1.f / lsum;
    int row = q0 + l15;
    int b = bh >> 3, hh = bh & 7;
    half2t lo = pkrtz(o[0] * inv, o[1] * inv);
    half2t hi = pkrtz(o[2] * inv, o[3] * inv);
    half4 hv; hv[0] = lo[0]; hv[1] = lo[1]; hv[2] = hi[0]; hv[3] = hi[1];
    *(half4*)(out16 + ((size_t)(b * Nq + row)) * Dq + hh * 16 + l4 * 4) = hv;
}

// ---------------- fused GEMM(Nc=128) + residual(h16) + LayerNorm -> h16 ----------------
__global__ __launch_bounds__(256) void hgemm_ln_kernel(const _Float16* __restrict__ A,
                                                       const _Float16* __restrict__ W,
                                                       const float* __restrict__ bias,
                                                       const float* __restrict__ lnw,
                                                       const float* __restrict__ lnb,
                                                       _Float16* __restrict__ h16,
                                                       int K) {
    int tid = threadIdx.x;
    int lane = tid & 63, w = tid >> 6;
    int l15 = lane & 15, l4 = lane >> 4;
    int m0 = blockIdx.x * 64 + w * 16;
    const _Float16* Ap = A + (size_t)(m0 + l15) * K + l4 * 4;
    const _Float16* Wp = W + (size_t)l15 * K + l4 * 4;
    v4f acc[8] = {};
    for (int ks = 0; ks < K; ks += 16) {
        half4 af = *(const half4*)(Ap + ks);
#pragma unroll
        for (int nt = 0; nt < 8; nt++) {
            half4 wf = *(const half4*)(Wp + (size_t)nt * 16 * K + ks);
            acc[nt] = __builtin_amdgcn_mfma_f32_16x16x16f16(wf, af, acc[nt], 0, 0, 0);
        }
    }
    int m = m0 + l15;
    float x[8][4];
    float psum = 0.f;
#pragma unroll
    for (int nt = 0; nt < 8; nt++) {
        int nb = nt * 16 + l4 * 4;
        float4 bv = *(const float4*)(bias + nb);
        half4 rv = *(const half4*)(h16 + (size_t)m * Dq + nb);
        x[nt][0] = acc[nt][0] + bv.x + (float)rv[0];
        x[nt][1] = acc[nt][1] + bv.y + (float)rv[1];
        x[nt][2] = acc[nt][2] + bv.z + (float)rv[2];
        x[nt][3] = acc[nt][3] + bv.w + (float)rv[3];
        psum += (x[nt][0] + x[nt][1]) + (x[nt][2] + x[nt][3]);
    }
    psum += __shfl_xor(psum, 16);
    psum += __shfl_xor(psum, 32);
    float mean = psum * (1.f / 128.f);
    float vsum = 0.f;
#pragma unroll
    for (int nt = 0; nt < 8; nt++)
#pragma unroll
        for (int r = 0; r < 4; r++) {
            x[nt][r] -= mean;
            vsum += x[nt][r] * x[nt][r];
        }
    vsum += __shfl_xor(vsum, 16);
    vsum += __shfl_xor(vsum, 32);
    float inv = rsqrtf(vsum * (1.f / 128.f) + EPSq);
#pragma unroll
    for (int nt = 0; nt < 8; nt++) {
        int nb = nt * 16 + l4 * 4;
        float4 wv = *(const float4*)(lnw + nb);
        float4 bb = *(const float4*)(lnb + nb);
        float y0 = x[nt][0] * inv * wv.x + bb.x;
        float y1 = x[nt][1] * inv * wv.y + bb.y;
        float y2 = x[nt][2] * inv * wv.z + bb.z;
        float y3 = x[nt][3] * inv * wv.w + bb.w;
        half2t lo = pkrtz(y0, y1);
        half2t hi = pkrtz(y2, y3);
        half4 hv2; hv2[0] = lo[0]; hv2[1] = lo[1]; hv2[2] = hi[0]; hv2[3] = hi[1];
        *(half4*)(h16 + (size_t)m * Dq + nb) = hv2;
    }
}

// ---------------- fused FFN (+ LN). LAST=1: emit per-wave column partial sums for pooling ----------------
template <int LAST>
__global__ __launch_bounds__(256) void ffn_kernel(const _Float16* __restrict__ h16in,
                                                  const _Float16* __restrict__ W1,
                                                  const float* __restrict__ b1,
                                                  const _Float16* __restrict__ W2,
                                                  const float* __restrict__ b2,
                                                  const float* __restrict__ lnw,
                                                  const float* __restrict__ lnb,
                                                  _Float16* __restrict__ h16,
                                                  float* __restrict__ part) {
    int tid = threadIdx.x;
    int lane = tid & 63, w = tid >> 6;
    int l15 = lane & 15, l4 = lane >> 4;
    int m0 = blockIdx.x * 64 + w * 16;
    int m = m0 + l15;
    const _Float16* Ap = h16in + (size_t)m * Dq + l4 * 4;
    half4 afr[8];
#pragma unroll
    for (int t = 0; t < 8; t++) afr[t] = *(const half4*)(Ap + t * 16);
    half4 mid[32];
#pragma unroll
    for (int c = 0; c < 8; c++) {
        v4f acc[4] = {};
#pragma unroll
        for (int t = 0; t < 8; t++) {
#pragma unroll
            for (int nt = 0; nt < 4; nt++) {
                half4 wf = *(const half4*)(W1 + (size_t)(c * 64 + nt * 16 + l15) * 128 + t * 16 + l4 * 4);
                acc[nt] = __builtin_amdgcn_mfma_f32_16x16x16f16(wf, afr[t], acc[nt], 0, 0, 0);
            }
        }
#pragma unroll
        for (int nt = 0; nt < 4; nt++) {
            float4 bv = *(const float4*)(b1 + c * 64 + nt * 16 + l4 * 4);
            float v0 = fmaxf(acc[nt][0] + bv.x, 0.f);
            float v1 = fmaxf(acc[nt][1] + bv.y, 0.f);
            float v2 = fmaxf(acc[nt][2] + bv.z, 0.f);
            float v3 = fmaxf(acc[nt][3] + bv.w, 0.f);
            half2t lo = pkrtz(v0, v1), hi = pkrtz(v2, v3);
            half4 hv; hv[0] = lo[0]; hv[1] = lo[1]; hv[2] = hi[0]; hv[3] = hi[1];
            mid[c * 4 + nt] = hv;
        }
    }
    v4f acc8[8] = {};
#pragma unroll 4
    for (int t = 0; t < 32; t++) {
#pragma unroll
        for (int nt = 0; nt < 8; nt++) {
            half4 wf = *(const half4*)(W2 + (size_t)(nt * 16 + l15) * 512 + t * 16 + l4 * 4);
            acc8[nt] = __builtin_amdgcn_mfma_f32_16x16x16f16(wf, mid[t], acc8[nt], 0, 0, 0);
        }
    }
    float x[8][4];
    float psum = 0.f;
#pragma unroll
    for (int nt = 0; nt < 8; nt++) {
        int nb = nt * 16 + l4 * 4;
        float4 bv = *(const float4*)(b2 + nb);
        x[nt][0] = acc8[nt][0] + bv.x + (float)afr[nt][0];
        x[nt][1] = acc8[nt][1] + bv.y + (float)afr[nt][1];
        x[nt][2] = acc8[nt][2] + bv.z + (float)afr[nt][2];
        x[nt][3] = acc8[nt][3] + bv.w + (float)afr[nt][3];
        psum += (x[nt][0] + x[nt][1]) + (x[nt][2] + x[nt][3]);
    }
    psum += __shfl_xor(psum, 16);
    psum += __shfl_xor(psum, 32);
    float mean = psum * (1.f / 128.f);
    float vsum = 0.f;
#pragma unroll
    for (int nt = 0; nt < 8; nt++)
#pragma unroll
        for (int r = 0; r < 4; r++) {
            x[nt][r] -= mean;
            vsum += x[nt][r] * x[nt][r];
        }
    vsum += __shfl_xor(vsum, 16);
    vsum += __shfl_xor(vsum, 32);
    float inv = rsqrtf(vsum * (1.f / 128.f) + EPSq);
#pragma unroll
    for (int nt = 0; nt < 8; nt++) {
        int nb = nt * 16 + l4 * 4;
        float4 wv = *(const float4*)(lnw + nb);
        float4 bb = *(const float4*)(lnb + nb);
        x[nt][0] = x[nt][0] * inv * wv.x + bb.x;
        x[nt][1] = x[nt][1] * inv * wv.y + bb.y;
        x[nt][2] = x[nt][2] * inv * wv.z + bb.z;
        x[nt][3] = x[nt][3] * inv * wv.w + bb.w;
        if (!LAST) {
            half2t lo = pkrtz(x[nt][0], x[nt][1]);
            half2t hi = pkrtz(x[nt][2], x[nt][3]);
            half4 hv2; hv2[0] = lo[0]; hv2[1] = lo[1]; hv2[2] = hi[0]; hv2[3] = hi[1];
            *(half4*)(h16 + (size_t)m * Dq + nb) = hv2;
        }
    }
    if (LAST) {
#pragma unroll
        for (int nt = 0; nt < 8; nt++)
#pragma unroll
            for (int r = 0; r < 4; r++) {
                float v = x[nt][r];
                v += __shfl_xor(v, 1);
                v += __shfl_xor(v, 2);
                v += __shfl_xor(v, 4);
                v += __shfl_xor(v, 8);
                x[nt][r] = v;
            }
        if (l15 == 0) {
            float* pp = part + ((size_t)blockIdx.x * 4 + w) * Dq;
#pragma unroll
            for (int nt = 0; nt < 8; nt++)
#pragma unroll
                for (int r = 0; r < 4; r++)
                    pp[nt * 16 + l4 * 4 + r] = x[nt][r];
        }
    }
}

// ---------------- head: pooled = mean over N via 256 wave-partials; MLP + sigmoid ----------------
__global__ __launch_bounds__(512) void head_kernel(const float* __restrict__ part,
                                                   const float* __restrict__ fc1_w, const float* __restrict__ fc1_b,
                                                   const float* __restrict__ fc2_w, const float* __restrict__ fc2_b,
                                                   float* __restrict__ out) {
    __shared__ float psh[Dq];
    __shared__ float red[512];
    int b = blockIdx.x, f = threadIdx.x;
    if (f < Dq) {
        float s = 0.f;
        for (int c = 0; c < 256; c++) s += part[((size_t)b * 256 + c) * Dq + f];
        psh[f] = s * (1.f / 4096.f);
    }
    __syncthreads();
    const float* wr = fc1_w + (size_t)f * Dq;
    float s = fc1_b[f];
    for (int d = 0; d < Dq; d++) s += psh[d] * wr[d];
    red[f] = fmaxf(s, 0.f) * fc2_w[f];
    __syncthreads();
    for (int st = 256; st > 0; st >>= 1) {
        if (f < st) red[f] += red[f + st];
        __syncthreads();
    }
    if (f == 0) out[b] = 1.f / (1.f + __expf(-(red[0] + fc2_b[0])));
}

extern "C" void kernel_launch(void* const* d_in, const int* in_sizes, int n_in,
                              void* d_out, int out_size, void* d_ws, size_t ws_size,
                              hipStream_t stream) {
    const float* x        = (const float*)d_in[0];
    const float* xyz_w    = (const float*)d_in[1];
    const float* xyz_b    = (const float*)d_in[2];
    const float* ohe_w    = (const float*)d_in[3];
    const float* ohe_b    = (const float*)d_in[4];
    const float* in_proj_w  = (const float*)d_in[5];
    const float* in_proj_b  = (const float*)d_in[6];
    const float* out_proj_w = (const float*)d_in[7];
    const float* out_proj_b = (const float*)d_in[8];
    const float* ln1_w    = (const float*)d_in[9];
    const float* ln1_b    = (const float*)d_in[10];
    const float* lin1_w   = (const float*)d_in[11];
    const float* lin1_b   = (const float*)d_in[12];
    const float* lin2_w   = (const float*)d_in[13];
    const float* lin2_b   = (const float*)d_in[14];
    const float* ln2_w    = (const float*)d_in[15];
    const float* ln2_b    = (const float*)d_in[16];
    const float* fc1_w    = (const float*)d_in[17];
    const float* fc1_b    = (const float*)d_in[18];
    const float* fc2_w    = (const float*)d_in[19];
    const float* fc2_b    = (const float*)d_in[20];
    float* outp = (float*)d_out;

    char* ws = (char*)d_ws;
    size_t off = 0;
    auto alloc = [&](size_t bytes) { void* p = ws + off; off += (bytes + 255) & ~255ULL; return p; };
    _Float16*  feat16 = (_Float16*)alloc((size_t)Bq * Nq * Dq * 2);
    _Float16*  h16    = (_Float16*)alloc((size_t)Bq * Nq * Dq * 2);
    _Float16*  abuf16 = (_Float16*)alloc((size_t)Bq * Nq * Dq * 2);
    _Float16*  pkb    = (_Float16*)alloc(3ull * 64 * Nq * 16 * 2);
    _Float16*  wb     = (_Float16*)alloc(393216ull * 2);
    int*       idx    = (int*)alloc((size_t)Bq * Nq * KNNq * 4);
    float*     part   = (float*)alloc(2048ull * Dq * 4);
    if (off > ws_size) return;

    const _Float16* wip16 = wb;
    const _Float16* wop16 = wb + 98304;
    const _Float16* wl116 = wb + 131072;
    const _Float16* wl216 = wb + 262144;

    int M = Bq * Nq;

    prep_kernel<<<16384 + 1536, 256, 0, stream>>>(x, xyz_w, xyz_b, ohe_w, ohe_b, feat16,
                                                  in_proj_w, out_proj_w, lin1_w, lin2_w, wb);
    knn_kernel<<<dim3(Nq / 64, Bq), 512, 0, stream>>>(x, idx);
    knn_attn_kernel<<<M / 4, 256, 0, stream>>>(feat16, idx, h16);

    for (int l = 0; l < Lq; l++) {
        hgemm_kernel<2><<<dim3(384 / 64, M / 64), 256, 0, stream>>>(
            h16, wip16 + (size_t)l * 384 * 128, in_proj_b + l * 384, pkb, M, 384, 128);
        flash9_kernel<<<dim3(Nq / 64, Bq * Hq), 256, 0, stream>>>(pkb, abuf16);
        hgemm_ln_kernel<<<M / 64, 256, 0, stream>>>(
            abuf16, wop16 + (size_t)l * 128 * 128, out_proj_b + l * 128,
            ln1_w + l * 128, ln1_b + l * 128, h16, 128);
        if (l == 0) {
            ffn_kernel<0><<<M / 64, 256, 0, stream>>>(
                h16, wl116, lin1_b, wl216, lin2_b, ln2_w, ln2_b, h16, part);
        } else {
            ffn_kernel<1><<<M / 64, 256, 0, stream>>>(
                h16, wl116 + (size_t)l * 512 * 128, lin1_b + l * 512,
                wl216 + (size_t)l * 128 * 512, lin2_b + l * 128,
                ln2_w + l * 128, ln2_b + l * 128, h16, part);
        }
    }

    head_kernel<<<Bq, 512, 0, stream>>>(part, fc1_w, fc1_b, fc2_w, fc2_b, outp);
}